// Round 1
// baseline (229.739 us; speedup 1.0000x reference)
//
#include <hip/hip_runtime.h>
#include <hip/hip_bf16.h>

// Problem constants: x [8, 64, 64, 64] fp32; N = 64*64 = 4096
#define BATCH 8
#define CH    64
#define CH2   32
#define NN    4096

typedef __attribute__((ext_vector_type(8))) short  short8;   // 8 bf16 = 4 VGPRs (MFMA A/B frag)
typedef __attribute__((ext_vector_type(4))) float  floatx4;  // MFMA C/D frag
typedef unsigned short ushort_t;

__device__ __forceinline__ unsigned short f2bf(float f) {
    // round-to-nearest-even fp32 -> bf16
    unsigned int u = __float_as_uint(f);
    unsigned int r = (u + 0x7FFFu + ((u >> 16) & 1u)) >> 16;
    return (unsigned short)r;
}

// ---------------- prep 1: x [B][C][N] fp32 -> xT [B][N][C] bf16 ----------------
__global__ __launch_bounds__(256) void prep_transpose(const float* __restrict__ x,
                                                      ushort_t* __restrict__ xT) {
    int idx = blockIdx.x * 256 + threadIdx.x;      // 0 .. B*N-1
    int b = idx >> 12;
    int n = idx & (NN - 1);
    const float* xp = x + (size_t)b * CH * NN + n; // stride-N reads, coalesced across threads
    ushort_t* dst = xT + (size_t)idx * CH;         // 128 B contiguous per thread
    #pragma unroll
    for (int i = 0; i < 8; ++i) {
        short8 v;
        #pragma unroll
        for (int j = 0; j < 8; ++j)
            v[j] = (short)f2bf(xp[(size_t)(i * 8 + j) * NN]);
        *(short8*)(dst + i * 8) = v;
    }
}

// ---------------- prep 2: g_x = g_w @ x + g_b, stored as gxT [B][32][N] bf16 (V^T) ----
__global__ __launch_bounds__(256) void prep_gx(const float* __restrict__ x,
                                               const float* __restrict__ gw,
                                               const float* __restrict__ gb,
                                               ushort_t* __restrict__ gxT) {
    __shared__ float gwl[CH2 * CH];
    __shared__ float gbl[CH2];
    int t = threadIdx.x;
    #pragma unroll
    for (int i = t; i < CH2 * CH; i += 256) gwl[i] = gw[i];
    if (t < CH2) gbl[t] = gb[t];
    __syncthreads();

    int idx = blockIdx.x * 256 + t;
    int b = idx >> 12;
    int n = idx & (NN - 1);
    const float* xp = x + (size_t)b * CH * NN + n;
    float acc[CH2];
    #pragma unroll
    for (int o = 0; o < CH2; ++o) acc[o] = gbl[o];
    #pragma unroll 4
    for (int c = 0; c < CH; ++c) {
        float xv = xp[(size_t)c * NN];
        #pragma unroll
        for (int o = 0; o < CH2; ++o) acc[o] += gwl[o * CH + c] * xv;
    }
    #pragma unroll
    for (int o = 0; o < CH2; ++o)
        gxT[((size_t)b * CH2 + o) * NN + n] = f2bf(acc[o]);
}

// ---------------- flash attention + output projection + residual ----------------
// grid = B * (N/64) = 512 blocks, 256 threads (4 waves). Wave w owns 16 query rows.
__global__ __launch_bounds__(256) void flash_attn(const ushort_t* __restrict__ xT,
                                                  const ushort_t* __restrict__ gxT,
                                                  const float* __restrict__ x,
                                                  const float* __restrict__ Ww,
                                                  const float* __restrict__ Wb,
                                                  float* __restrict__ out) {
    __shared__ ushort_t Klds[64 * 72];      // key-tile [key][ch], pad 72 vs 64
    __shared__ ushort_t Vlds[32 * 72];      // V^T tile [ch][key], pad 72
    __shared__ ushort_t Plds[4][16 * 72];   // per-wave P [row][key], pad 72

    const int tid  = threadIdx.x;
    const int wave = tid >> 6;
    const int lane = tid & 63;
    const int ql   = lane & 15;   // row/col-in-16 index
    const int quad = lane >> 4;   // 0..3

    const int b  = blockIdx.x >> 6;
    const int qt = blockIdx.x & 63;
    const int n0 = qt * 64 + wave * 16;    // this wave's first query row

    // Q fragments (A operand), K = 64 channels -> 2 slices of 32
    short8 qf[2];
    {
        const ushort_t* qp = xT + ((size_t)(b * NN + n0 + ql)) * CH + quad * 8;
        qf[0] = *(const short8*)(qp);
        qf[1] = *(const short8*)(qp + 32);
    }

    floatx4 yfrag[2];
    #pragma unroll
    for (int h = 0; h < 2; ++h) yfrag[h] = (floatx4){0.f, 0.f, 0.f, 0.f};
    float m_r[4], l_r[4];
    #pragma unroll
    for (int r = 0; r < 4; ++r) { m_r[r] = -1e30f; l_r[r] = 0.f; }

    const float LOG2E = 1.4426950408889634f;

    for (int kt = 0; kt < NN / 64; ++kt) {
        __syncthreads();   // previous iteration's LDS reads complete
        // stage K tile (64 keys x 64 ch = 8 KB): 2 x 16B per thread
        #pragma unroll
        for (int i = 0; i < 2; ++i) {
            int idx = tid + i * 256;          // 0..511
            int key = idx >> 3;
            int c0  = (idx & 7) * 8;
            short8 v = *(const short8*)(xT + ((size_t)(b * NN + kt * 64 + key)) * CH + c0);
            *(short8*)(Klds + key * 72 + c0) = v;
        }
        // stage V^T tile (32 ch x 64 keys = 4 KB): 1 x 16B per thread
        {
            int ch = tid >> 3;
            int k0 = (tid & 7) * 8;
            short8 v = *(const short8*)(gxT + ((size_t)(b * CH2 + ch)) * NN + kt * 64 + k0);
            *(short8*)(Vlds + ch * 72 + k0) = v;
        }
        __syncthreads();

        // QK^T: S[16 rows][64 keys] in 4 C-frags
        floatx4 sfrag[4];
        #pragma unroll
        for (int ct = 0; ct < 4; ++ct) {
            floatx4 acc = (floatx4){0.f, 0.f, 0.f, 0.f};
            #pragma unroll
            for (int ss = 0; ss < 2; ++ss) {
                short8 kf = *(const short8*)(Klds + (ct * 16 + ql) * 72 + ss * 32 + quad * 8);
                acc = __builtin_amdgcn_mfma_f32_16x16x32_bf16(qf[ss], kf, acc, 0, 0, 0);
            }
            sfrag[ct] = acc;
        }

        // online softmax (row = quad*4 + r, cols live across the 16 lanes of the quad)
        float alpha[4];
        #pragma unroll
        for (int r = 0; r < 4; ++r) {
            float t = fmaxf(fmaxf(sfrag[0][r], sfrag[1][r]), fmaxf(sfrag[2][r], sfrag[3][r]));
            t = fmaxf(t, __shfl_xor(t, 1));
            t = fmaxf(t, __shfl_xor(t, 2));
            t = fmaxf(t, __shfl_xor(t, 4));
            t = fmaxf(t, __shfl_xor(t, 8));
            float mn = fmaxf(m_r[r], t);
            alpha[r] = exp2f((m_r[r] - mn) * LOG2E);
            m_r[r] = mn;
        }
        #pragma unroll
        for (int h = 0; h < 2; ++h)
            #pragma unroll
            for (int r = 0; r < 4; ++r) yfrag[h][r] *= alpha[r];

        // P = exp(S - m) -> bf16, through per-wave LDS (C/D layout -> A layout)
        ushort_t* Pw = Plds[wave];
        float rs[4] = {0.f, 0.f, 0.f, 0.f};
        #pragma unroll
        for (int ct = 0; ct < 4; ++ct) {
            #pragma unroll
            for (int r = 0; r < 4; ++r) {
                float p = exp2f((sfrag[ct][r] - m_r[r]) * LOG2E);
                rs[r] += p;
                Pw[(quad * 4 + r) * 72 + ct * 16 + ql] = f2bf(p);
            }
        }
        #pragma unroll
        for (int r = 0; r < 4; ++r) {
            float t = rs[r];
            t += __shfl_xor(t, 1);
            t += __shfl_xor(t, 2);
            t += __shfl_xor(t, 4);
            t += __shfl_xor(t, 8);
            l_r[r] = l_r[r] * alpha[r] + t;
        }

        // PV: y[16 rows][32 ch] += P[16][64] * V[64][32]
        #pragma unroll
        for (int ss = 0; ss < 2; ++ss) {
            short8 pf = *(const short8*)(Pw + ql * 72 + ss * 32 + quad * 8);
            #pragma unroll
            for (int h = 0; h < 2; ++h) {
                short8 vf = *(const short8*)(Vlds + (h * 16 + ql) * 72 + ss * 32 + quad * 8);
                yfrag[h] = __builtin_amdgcn_mfma_f32_16x16x32_bf16(pf, vf, yfrag[h], 0, 0, 0);
            }
        }
    }

    // normalize
    #pragma unroll
    for (int h = 0; h < 2; ++h)
        #pragma unroll
        for (int r = 0; r < 4; ++r) yfrag[h][r] /= l_r[r];

    __syncthreads();
    // stage Ww fp32 [64][32] into Klds region, padded to 33 to dodge bank conflicts
    float* WwL = (float*)Klds;   // 64*33*4 = 8448 B <= 9216 B
    #pragma unroll
    for (int i = tid; i < CH * CH2; i += 256) WwL[(i >> 5) * 33 + (i & 31)] = Ww[i];
    // park y in per-wave LDS: [16 rows][32 ch] fp32 (2048 B <= 2304 B)
    float* yb = (float*)Plds[wave];
    #pragma unroll
    for (int h = 0; h < 2; ++h)
        #pragma unroll
        for (int r = 0; r < 4; ++r)
            yb[(quad * 4 + r) * 32 + h * 16 + ql] = yfrag[h][r];
    __syncthreads();

    // output projection + bias + residual. Lane handles row n = n0+ql, channels c = i*4+quad.
    float yreg[CH2];
    #pragma unroll
    for (int o = 0; o < CH2; ++o) yreg[o] = yb[ql * 32 + o];

    const int n = n0 + ql;
    #pragma unroll
    for (int i = 0; i < 16; ++i) {
        int c = i * 4 + quad;
        float acc = Wb[c];
        #pragma unroll
        for (int o = 0; o < CH2; ++o) acc += WwL[c * 33 + o] * yreg[o];
        size_t oidx = ((size_t)b * CH + c) * NN + n;
        out[oidx] = acc + x[oidx];
    }
}

extern "C" void kernel_launch(void* const* d_in, const int* in_sizes, int n_in,
                              void* d_out, int out_size, void* d_ws, size_t ws_size,
                              hipStream_t stream) {
    const float* x  = (const float*)d_in[0];
    const float* gw = (const float*)d_in[1];
    const float* gb = (const float*)d_in[2];
    const float* Ww = (const float*)d_in[3];
    const float* Wb = (const float*)d_in[4];
    float* out = (float*)d_out;

    // workspace: xT bf16 [B][N][64] = 4 MB, gxT bf16 [B][32][N] = 2 MB
    ushort_t* xT  = (ushort_t*)d_ws;
    ushort_t* gxT = xT + (size_t)BATCH * NN * CH;

    hipLaunchKernelGGL(prep_transpose, dim3(BATCH * NN / 256), dim3(256), 0, stream, x, xT);
    hipLaunchKernelGGL(prep_gx,        dim3(BATCH * NN / 256), dim3(256), 0, stream, x, gw, gb, gxT);
    hipLaunchKernelGGL(flash_attn,     dim3(BATCH * (NN / 64)), dim3(256), 0, stream,
                       xT, gxT, x, Ww, Wb, out);
}

// Round 2
// 170.174 us; speedup vs baseline: 1.3500x; 1.3500x over previous
//
#include <hip/hip_runtime.h>
#include <hip/hip_bf16.h>

#define BATCH 8
#define CH    64
#define CH2   32
#define NN    4096
#define BN    (BATCH * NN)   // 32768 rows total

typedef __attribute__((ext_vector_type(8))) short  short8;   // 8 bf16 (MFMA A/B frag)
typedef __attribute__((ext_vector_type(4))) float  floatx4;  // MFMA C/D frag
typedef unsigned short ushort_t;

#define LOG2E 1.4426950408889634f

__device__ __forceinline__ unsigned short f2bf_rne(float f) {
    unsigned int u = __float_as_uint(f);
    return (unsigned short)((u + 0x7FFFu + ((u >> 16) & 1u)) >> 16);
}
// round-half-up: 2 VALU ops, fine for P in [0,1]
__device__ __forceinline__ unsigned short f2bf_fast(float f) {
    unsigned int u = __float_as_uint(f);
    return (unsigned short)((u + 0x8000u) >> 16);
}

// ---- prep 1: x [B][C][N] fp32 -> xT [B*N][64] bf16, plus mlog[row] = 12*||x_row||*log2(e)
// grid = BN*4/256 = 512 blocks; 4 threads per row, 16 channels each.
__global__ __launch_bounds__(256) void prep_xt(const float* __restrict__ x,
                                               ushort_t* __restrict__ xT,
                                               float* __restrict__ mlog) {
    int g   = blockIdx.x * 256 + threadIdx.x;
    int row = g >> 2;
    int q4  = g & 3;
    int b = row >> 12, n = row & (NN - 1);
    const float* xp = x + (size_t)b * CH * NN + n;
    float ns = 0.f;
    short8 v0, v1;
    #pragma unroll
    for (int j = 0; j < 8; ++j) {
        float a = xp[(size_t)(q4 * 16 + j) * NN];
        ns += a * a;
        v0[j] = (short)f2bf_rne(a);
    }
    #pragma unroll
    for (int j = 0; j < 8; ++j) {
        float a = xp[(size_t)(q4 * 16 + 8 + j) * NN];
        ns += a * a;
        v1[j] = (short)f2bf_rne(a);
    }
    *(short8*)(xT + (size_t)row * CH + q4 * 16)     = v0;
    *(short8*)(xT + (size_t)row * CH + q4 * 16 + 8) = v1;
    ns += __shfl_xor(ns, 1);
    ns += __shfl_xor(ns, 2);
    if (q4 == 0) mlog[row] = 12.0f * sqrtf(ns) * LOG2E;
}

// ---- prep 2: g_x = g_w @ x + g_b -> gxT [B][32 och][N] bf16 (V^T layout)
// grid = BN/128 = 256 blocks; 2 threads per column n, 16 och each.
__global__ __launch_bounds__(256) void prep_gx(const float* __restrict__ x,
                                               const float* __restrict__ gw,
                                               const float* __restrict__ gb,
                                               ushort_t* __restrict__ gxT) {
    __shared__ float gwl[CH2 * CH];
    __shared__ float gbl[CH2];
    int t = threadIdx.x;
    for (int i = t; i < CH2 * CH; i += 256) gwl[i] = gw[i];
    if (t < CH2) gbl[t] = gb[t];
    __syncthreads();
    int half = t >> 7;
    int g = blockIdx.x * 128 + (t & 127);
    int b = g >> 12, n = g & (NN - 1);
    const float* xp = x + (size_t)b * CH * NN + n;
    float acc[16];
    #pragma unroll
    for (int o = 0; o < 16; ++o) acc[o] = gbl[half * 16 + o];
    for (int c = 0; c < CH; ++c) {
        float xv = xp[(size_t)c * NN];
        #pragma unroll
        for (int o = 0; o < 16; ++o) acc[o] += gwl[(half * 16 + o) * CH + c] * xv;
    }
    #pragma unroll
    for (int o = 0; o < 16; ++o)
        gxT[((size_t)b * CH2 + half * 16 + o) * NN + n] = f2bf_rne(acc[o]);
}

// ---- flash attention with fixed per-row shift, split-K partials
// grid = 512 * nsplit blocks, 256 threads (4 waves), wave owns 16 query rows.
__global__ __launch_bounds__(256, 4) void flash_attn(const ushort_t* __restrict__ xT,
                                                     const ushort_t* __restrict__ gxT,
                                                     const float* __restrict__ mlog,
                                                     float* __restrict__ py,
                                                     float* __restrict__ pl,
                                                     int ksplit) {
    __shared__ ushort_t Klds[64 * 72];      // key tile [key][ch], stride 72 (16B-aligned rows)
    __shared__ ushort_t Plds[4][16 * 72];   // per-wave P [row][key]

    const int tid = threadIdx.x, wave = tid >> 6, lane = tid & 63;
    const int ql = lane & 15, quad = lane >> 4;
    const int bq = blockIdx.x & 511;        // 512 = BATCH*64
    const int sp = blockIdx.x >> 9;
    const int b = bq >> 6, qt = bq & 63;
    const int n0 = qt * 64 + wave * 16;
    const int k0 = sp * ksplit;

    short8 qf[2];
    {
        const ushort_t* qp = xT + ((size_t)(b * NN + n0 + ql)) * CH + quad * 8;
        qf[0] = *(const short8*)qp;
        qf[1] = *(const short8*)(qp + 32);
    }
    float mlr[4];
    {
        float4 m4 = *(const float4*)(mlog + (size_t)b * NN + n0 + quad * 4);
        mlr[0] = m4.x; mlr[1] = m4.y; mlr[2] = m4.z; mlr[3] = m4.w;
    }

    floatx4 yf[2];
    yf[0] = (floatx4){0.f, 0.f, 0.f, 0.f};
    yf[1] = (floatx4){0.f, 0.f, 0.f, 0.f};
    float rs[4] = {0.f, 0.f, 0.f, 0.f};

    const ushort_t* kbase = xT + (size_t)(b * NN + k0) * CH;
    const ushort_t* vbase = gxT + (size_t)(b * CH2) * NN + k0;

    const int iters = ksplit >> 6;
    for (int kt = 0; kt < iters; ++kt) {
        // prefetch V fragments (global, L2-resident) and K staging chunks before the barrier
        short8 vf[2][2];
        #pragma unroll
        for (int ss = 0; ss < 2; ++ss)
            #pragma unroll
            for (int h = 0; h < 2; ++h)
                vf[ss][h] = *(const short8*)(vbase + (size_t)(h * 16 + ql) * NN +
                                             kt * 64 + ss * 32 + quad * 8);
        short8 kv[2];
        int key[2], c0[2];
        #pragma unroll
        for (int i = 0; i < 2; ++i) {
            int idx = tid + i * 256;
            key[i] = idx >> 3; c0[i] = (idx & 7) * 8;
            kv[i] = *(const short8*)(kbase + (size_t)(kt * 64 + key[i]) * CH + c0[i]);
        }
        __syncthreads();   // all waves done reading previous K tile
        #pragma unroll
        for (int i = 0; i < 2; ++i)
            *(short8*)(Klds + key[i] * 72 + c0[i]) = kv[i];
        __syncthreads();

        // QK^T: S[16 rows][64 keys]
        floatx4 sf[4];
        #pragma unroll
        for (int ct = 0; ct < 4; ++ct) {
            floatx4 acc = (floatx4){0.f, 0.f, 0.f, 0.f};
            #pragma unroll
            for (int ss = 0; ss < 2; ++ss) {
                short8 kf = *(const short8*)(Klds + (ct * 16 + ql) * 72 + ss * 32 + quad * 8);
                acc = __builtin_amdgcn_mfma_f32_16x16x32_bf16(qf[ss], kf, acc, 0, 0, 0);
            }
            sf[ct] = acc;
        }

        // P = exp2(S*log2e - mlog) -> bf16 into per-wave LDS (C-layout -> A-layout)
        ushort_t* Pw = Plds[wave];
        #pragma unroll
        for (int ct = 0; ct < 4; ++ct) {
            #pragma unroll
            for (int r = 0; r < 4; ++r) {
                float p = exp2f(fmaf(sf[ct][r], LOG2E, -mlr[r]));
                rs[r] += p;
                Pw[(quad * 4 + r) * 72 + ct * 16 + ql] = f2bf_fast(p);
            }
        }

        // PV: y[16][32] += P[16][64] * V[64][32]
        #pragma unroll
        for (int ss = 0; ss < 2; ++ss) {
            short8 pf = *(const short8*)(Pw + ql * 72 + ss * 32 + quad * 8);
            #pragma unroll
            for (int h = 0; h < 2; ++h)
                yf[h] = __builtin_amdgcn_mfma_f32_16x16x32_bf16(pf, vf[ss][h], yf[h], 0, 0, 0);
        }
    }

    // epilogue: reduce l across the 16 cols, write partials
    #pragma unroll
    for (int r = 0; r < 4; ++r) {
        rs[r] += __shfl_xor(rs[r], 1);
        rs[r] += __shfl_xor(rs[r], 2);
        rs[r] += __shfl_xor(rs[r], 4);
        rs[r] += __shfl_xor(rs[r], 8);
    }
    size_t rowg = (size_t)b * NN + n0 + quad * 4;
    #pragma unroll
    for (int r = 0; r < 4; ++r) {
        #pragma unroll
        for (int h = 0; h < 2; ++h)
            py[((size_t)sp * BN + rowg + r) * CH2 + h * 16 + ql] = yf[h][r];
        if (ql == 0) pl[(size_t)sp * BN + rowg + r] = rs[r];
    }
}

// ---- reduction over splits + normalize + output projection + bias + residual
// grid = BN/64 = 512 blocks; 4 threads per row n (16 out-channels each).
__global__ __launch_bounds__(256) void reduce_proj(const float* __restrict__ py,
                                                   const float* __restrict__ pl,
                                                   const float* __restrict__ Ww,
                                                   const float* __restrict__ Wb,
                                                   const float* __restrict__ x,
                                                   float* __restrict__ out,
                                                   int nsplit) {
    __shared__ float WwL[CH * 33];
    __shared__ float WbL[CH];
    int t = threadIdx.x;
    for (int i = t; i < CH * CH2; i += 256) WwL[(i >> 5) * 33 + (i & 31)] = Ww[i];
    if (t < CH) WbL[t] = Wb[t];
    __syncthreads();
    int quarter = t >> 6;
    int ng = blockIdx.x * 64 + (t & 63);
    int b = ng >> 12, n = ng & (NN - 1);
    float y[CH2];
    #pragma unroll
    for (int o = 0; o < CH2; ++o) y[o] = 0.f;
    float l = 0.f;
    for (int s = 0; s < nsplit; ++s) {
        l += pl[(size_t)s * BN + ng];
        const float4* yp = (const float4*)(py + ((size_t)s * BN + ng) * CH2);
        #pragma unroll
        for (int o4 = 0; o4 < 8; ++o4) {
            float4 v = yp[o4];
            y[o4 * 4 + 0] += v.x; y[o4 * 4 + 1] += v.y;
            y[o4 * 4 + 2] += v.z; y[o4 * 4 + 3] += v.w;
        }
    }
    float inv = 1.0f / l;
    #pragma unroll
    for (int o = 0; o < CH2; ++o) y[o] *= inv;
    #pragma unroll
    for (int i = 0; i < 16; ++i) {
        int c = quarter * 16 + i;
        float acc = WbL[c];
        #pragma unroll
        for (int o = 0; o < CH2; ++o) acc = fmaf(WwL[c * 33 + o], y[o], acc);
        size_t oi = ((size_t)b * CH + c) * NN + n;
        out[oi] = acc + x[oi];
    }
}

extern "C" void kernel_launch(void* const* d_in, const int* in_sizes, int n_in,
                              void* d_out, int out_size, void* d_ws, size_t ws_size,
                              hipStream_t stream) {
    const float* x  = (const float*)d_in[0];
    const float* gw = (const float*)d_in[1];
    const float* gb = (const float*)d_in[2];
    const float* Ww = (const float*)d_in[3];
    const float* Wb = (const float*)d_in[4];
    float* out = (float*)d_out;

    // workspace layout
    ushort_t* xT   = (ushort_t*)d_ws;                        // BN*64 bf16   = 4 MB
    ushort_t* gxT  = xT + (size_t)BN * CH;                   // B*32*N bf16  = 2 MB
    float*    mlog = (float*)(gxT + (size_t)BATCH * CH2 * NN); // BN fp32    = 128 KB
    float*    py   = mlog + BN;                              // split*BN*32 fp32
    size_t base_bytes = (size_t)BN * CH * 2 + (size_t)BATCH * CH2 * NN * 2 + (size_t)BN * 4;
    int split = 4;
    while (split > 1 && base_bytes + (size_t)split * BN * (CH2 + 1) * 4 > ws_size)
        split >>= 1;
    float* pl = py + (size_t)split * BN * CH2;

    hipLaunchKernelGGL(prep_xt,     dim3(BN * 4 / 256), dim3(256), 0, stream, x, xT, mlog);
    hipLaunchKernelGGL(prep_gx,     dim3(BN / 128),     dim3(256), 0, stream, x, gw, gb, gxT);
    hipLaunchKernelGGL(flash_attn,  dim3(512 * split),  dim3(256), 0, stream,
                       xT, gxT, mlog, py, pl, NN / split);
    hipLaunchKernelGGL(reduce_proj, dim3(BN / 64),      dim3(256), 0, stream,
                       py, pl, Ww, Wb, x, out, split);
}